// Round 9
// baseline (376.289 us; speedup 1.0000x reference)
//
#include <hip/hip_runtime.h>
#include <stdint.h>

// ---------------------------------------------------------------------------
// GPT2 attention forward, fp32 in/out, bf16 MFMA internally.
// Round 9: (1) attn -> 4-wave blocks, K/V staged to LDS cooperatively with
// contiguous 128B-coalesced loads (8x fewer L2 requests than per-wave direct
// fragments, 4x less traffic) + register prefetch of tile j+1 across the
// barrier; sum-balanced block pairing. (2) GEMM staging -> async
// global_load_lds width 16 (m97 pattern; r1/r2 NaN was the fp32 dtype bug,
// not this builtin).
// ---------------------------------------------------------------------------

typedef __bf16 bf16x8 __attribute__((ext_vector_type(8)));
typedef float f32x4 __attribute__((ext_vector_type(4)));

__device__ __forceinline__ f32x4 mfma16(bf16x8 a, bf16x8 b, f32x4 c) {
  return __builtin_amdgcn_mfma_f32_16x16x32_bf16(a, b, c, 0, 0, 0);
}

// async global->LDS, 16B/lane: lane i's 16B -> ldsbase + i*16 (wave-uniform base)
__device__ __forceinline__ void g2l16(const void* g, void* l) {
  __builtin_amdgcn_global_load_lds(
      (const __attribute__((address_space(1))) unsigned int*)g,
      (__attribute__((address_space(3))) unsigned int*)l,
      16, 0, 0);
}

__device__ __forceinline__ uint16_t f2bf(float f) {
  unsigned int u = __builtin_bit_cast(unsigned int, f);
  u += 0x7fffu + ((u >> 16) & 1u);
  return (uint16_t)(u >> 16);
}

// ---------------------------------------------------------------------------
// fp32 -> bf16 elementwise, 8 elements/thread.
// ---------------------------------------------------------------------------
__global__ __launch_bounds__(256) void f2b_k(const float* __restrict__ in,
                                             uint16_t* __restrict__ out, int n) {
  const int base = (blockIdx.x * 256 + threadIdx.x) * 8;
  if (base >= n) return;
  float4 a = *(const float4*)(in + base);
  float4 b = *(const float4*)(in + base + 4);
  uint16_t t[8];
  t[0] = f2bf(a.x); t[1] = f2bf(a.y); t[2] = f2bf(a.z); t[3] = f2bf(a.w);
  t[4] = f2bf(b.x); t[5] = f2bf(b.y); t[6] = f2bf(b.z); t[7] = f2bf(b.w);
  *(int4*)(out + base) = *(const int4*)t;
}

// ---------------------------------------------------------------------------
// fused convert+transpose: out_bf16[c][r] = in_f32[r][c]. grid (C/64, R/64).
// ---------------------------------------------------------------------------
__global__ __launch_bounds__(256) void transpose_f2b(const float* __restrict__ in,
                                                     uint16_t* __restrict__ out,
                                                     int R, int C) {
  __shared__ float t[64][65];
  const int tx = threadIdx.x & 15;
  const int ty = threadIdx.x >> 4;
  const int r0 = blockIdx.y * 64, c0 = blockIdx.x * 64;
#pragma unroll
  for (int rr = ty; rr < 64; rr += 16) {
    float4 v = *(const float4*)(in + (size_t)(r0 + rr) * C + c0 + tx * 4);
    t[rr][tx * 4 + 0] = v.x; t[rr][tx * 4 + 1] = v.y;
    t[rr][tx * 4 + 2] = v.z; t[rr][tx * 4 + 3] = v.w;
  }
  __syncthreads();
#pragma unroll
  for (int cc = ty; cc < 64; cc += 16) {
    uint16_t tmp[4];
#pragma unroll
    for (int j = 0; j < 4; j++) tmp[j] = f2bf(t[tx * 4 + j][cc]);
    *(uint2*)(out + (size_t)(c0 + cc) * R + r0 + tx * 4) = *(const uint2*)tmp;
  }
}

// ---------------------------------------------------------------------------
// bt-form GEMM: C[m][n] = A[m][:].Bt[n][:] + bias[n]. A,Bt bf16; bias fp32.
// K=1024, tile 128x128, async global_load_lds staging (width 16).
// EPI==0: QKV scatter (Q prescaled 0.125; outV = V^T [h][d][s]) -> bf16
// EPI==1: plain fp32 epilogue (outF[m*1024+n])
// ---------------------------------------------------------------------------
template <int EPI>
__global__ __launch_bounds__(256) void gemm_bt(const uint16_t* __restrict__ A,
                                               const uint16_t* __restrict__ Bt,
                                               const float* __restrict__ bias,
                                               uint16_t* __restrict__ outQ,
                                               uint16_t* __restrict__ outK,
                                               uint16_t* __restrict__ outV,
                                               float* __restrict__ outF) {
  __shared__ __align__(16) uint16_t lA[128 * 32];
  __shared__ __align__(16) uint16_t lB[128 * 32];
  const int tid = threadIdx.x;
  const int w = tid >> 6, lane = tid & 63;
  const int quad = lane >> 4, c16 = lane & 15;
  const int m0 = blockIdx.y * 128, n0 = blockIdx.x * 128;

  f32x4 acc[4][4];
#pragma unroll
  for (int i = 0; i < 4; i++)
#pragma unroll
    for (int j = 0; j < 4; j++) acc[i][j] = f32x4{0.f, 0.f, 0.f, 0.f};

  // LDS row = 64B = 4 chunks of 16B; chunk swizzle c' = c ^ ((row>>1)&3).
  for (int k0 = 0; k0 < 1024; k0 += 32) {
    __syncthreads();
#pragma unroll
    for (int ii = 0; ii < 2; ii++) {
      const int instr = w * 2 + ii;
      const int p16 = instr * 64 + lane;  // 0..511
      const int row = p16 >> 2, cp = p16 & 3;
      const int c = cp ^ ((row >> 1) & 3);
      g2l16(A + (size_t)(m0 + row) * 1024 + k0 + c * 8, (char*)lA + (size_t)instr * 1024);
      g2l16(Bt + (size_t)(n0 + row) * 1024 + k0 + c * 8, (char*)lB + (size_t)instr * 1024);
    }
    __syncthreads();
    bf16x8 af[4], bfr[4];
#pragma unroll
    for (int t = 0; t < 4; t++) {
      const int mr = (w >> 1) * 64 + t * 16 + c16;
      af[t] = *(const bf16x8*)((const char*)lA + mr * 64 + ((quad ^ ((mr >> 1) & 3)) * 16));
      const int nr = (w & 1) * 64 + t * 16 + c16;
      bfr[t] = *(const bf16x8*)((const char*)lB + nr * 64 + ((quad ^ ((nr >> 1) & 3)) * 16));
    }
#pragma unroll
    for (int i = 0; i < 4; i++)
#pragma unroll
      for (int j = 0; j < 4; j++) acc[i][j] = mfma16(af[i], bfr[j], acc[i][j]);
  }

  // epilogue. C/D layout per 16x16 tile: col = lane&15, row = quad*4+r.
  const int mbase = m0 + (w >> 1) * 64;
  const int nbase = n0 + (w & 1) * 64;
  float bv[4];
#pragma unroll
  for (int j = 0; j < 4; j++) bv[j] = bias[nbase + j * 16 + c16];
#pragma unroll
  for (int i = 0; i < 4; i++) {
#pragma unroll
    for (int j = 0; j < 4; j++) {
      const int n = nbase + j * 16 + c16;
#pragma unroll
      for (int r = 0; r < 4; r++) {
        const int m = mbase + i * 16 + quad * 4 + r;
        float fv = acc[i][j][r] + bv[j];
        if (EPI == 0) {
          const int region = n >> 10;  // 0=Q 1=K 2=V (uniform per block)
          const int cr = n & 1023;
          const int h = cr >> 6, d = cr & 63;
          if (region == 0)      outQ[((size_t)(h << 12) + m) * 64 + d] = f2bf(fv * 0.125f);
          else if (region == 1) outK[((size_t)(h << 12) + m) * 64 + d] = f2bf(fv);
          else                  outV[((size_t)(h * 64 + d) << 12) + m] = f2bf(fv);  // V^T
        } else {
          outF[(size_t)m * 1024 + n] = fv;
        }
      }
    }
  }
}

// ---------------------------------------------------------------------------
// Flash attention. 4 waves/block, block owns 128 q rows of one head.
// K/V tiles staged to LDS cooperatively (contiguous, 128B-coalesced) with a
// register prefetch of tile j+1 held across the compute of tile j; 2 barriers
// per iter. lP is per-wave. Grid 512: bid<256 -> qt=31-(bid>>4) (heavy),
// bid>=256 -> qt=(bid-256)>>4 (light) — each CU's pair sums ~32 iters.
// h = bid&15 -> XCD pinning of each head's KV.
// ---------------------------------------------------------------------------
__global__ __launch_bounds__(256, 2) void attn_kernel(const uint16_t* __restrict__ Qb,
                                                      const uint16_t* __restrict__ Kb,
                                                      const uint16_t* __restrict__ Vtb,
                                                      uint16_t* __restrict__ Ob) {
  __shared__ __align__(16) uint16_t lK[128 * 64];      // [key][d], swizzled chunks
  __shared__ __align__(16) uint16_t lV[64 * 128];      // [d][key], swizzled chunks
  __shared__ __align__(16) uint16_t lP[4 * 32 * 128];  // per-wave [q][key]
  const int tid = threadIdx.x;
  const int w = tid >> 6, lane = tid & 63;
  const int quad = lane >> 4, c16 = lane & 15;
  const int bid = blockIdx.x;
  const int qt = (bid < 256) ? (31 - (bid >> 4)) : ((bid - 256) >> 4);
  const int h = bid & 15;
  const int q0w = qt * 128 + w * 32;
  const int jmax = qt;  // uniform across the block

  // Q fragments (B-operand): lane holds q(n)=c16, k(d) = kc*32 + quad*8 + j
  bf16x8 qf[2][2];
#pragma unroll
  for (int nt = 0; nt < 2; nt++)
#pragma unroll
    for (int kc = 0; kc < 2; kc++) {
      int4 v = *(const int4*)(Qb + ((size_t)(h << 12) + q0w + nt * 16 + c16) * 64 + kc * 32 + quad * 8);
      qf[nt][kc] = __builtin_bit_cast(bf16x8, v);
    }

  float ms[2] = {-3.0e38f, -3.0e38f};
  float ls[2] = {0.f, 0.f};
  f32x4 o[4][2];
#pragma unroll
  for (int i = 0; i < 4; i++) { o[i][0] = f32x4{0.f,0.f,0.f,0.f}; o[i][1] = f32x4{0.f,0.f,0.f,0.f}; }

  // staging registers (tile j+1)
  int4 rk[4], rv[4];

  // ---- load a tile into rk/rv (contiguous, fully coalesced) ----
  auto load_tile = [&](int j) {
#pragma unroll
    for (int i = 0; i < 4; i++) {
      const int p = i * 256 + tid;               // 0..1023 int4 slots
      rk[i] = *(const int4*)(Kb + ((size_t)(h << 12) + j * 128) * 64 + (size_t)p * 8);
      const int d = p >> 4, c = p & 15;
      rv[i] = *(const int4*)(Vtb + ((size_t)(h * 64 + d) << 12) + j * 128 + c * 8);
    }
  };
  // ---- write rk/rv into swizzled LDS layout ----
  auto write_tile = [&]() {
#pragma unroll
    for (int i = 0; i < 4; i++) {
      const int p = i * 256 + tid;
      const int rowK = p >> 3, cK = p & 7;       // 8 chunks per 128B K row
      *(int4*)((char*)lK + rowK * 128 + ((cK ^ (rowK & 7)) << 4)) = rk[i];
      const int dV = p >> 4, cV = p & 15;        // 16 chunks per 256B V row
      *(int4*)((char*)lV + dV * 256 + ((cV ^ (dV & 15)) << 4)) = rv[i];
    }
  };

  // prologue: stage tile 0
  load_tile(0);
  write_tile();
  __syncthreads();
  if (jmax >= 1) load_tile(1);

  for (int j = 0;; j++) {
    // ---- S^T = K . Q^T : D[key][q], 8 key-tiles x 2 q-tiles
    f32x4 st[8][2];
#pragma unroll
    for (int mt = 0; mt < 8; mt++) { st[mt][0] = f32x4{0.f,0.f,0.f,0.f}; st[mt][1] = f32x4{0.f,0.f,0.f,0.f}; }
#pragma unroll
    for (int kc = 0; kc < 2; kc++)
#pragma unroll
      for (int mt = 0; mt < 8; mt++) {
        const int row = mt * 16 + c16;
        bf16x8 a = *(const bf16x8*)((const char*)lK + row * 128 + (((kc * 4 + quad) ^ (row & 7)) * 16));
        st[mt][0] = mfma16(a, qf[0][kc], st[mt][0]);
        st[mt][1] = mfma16(a, qf[1][kc], st[mt][1]);
      }

    // ---- causal mask on the diagonal tile (uniform branch)
    if (j == jmax) {
#pragma unroll
      for (int nt = 0; nt < 2; nt++) {
        const int qg = q0w + nt * 16 + c16;
#pragma unroll
        for (int mt = 0; mt < 8; mt++)
#pragma unroll
          for (int r = 0; r < 4; r++) {
            const int key = j * 128 + mt * 16 + quad * 4 + r;
            if (key > qg) st[mt][nt][r] = -1.0e9f;
          }
      }
    }

    // ---- online softmax (per q = c16, state replicated across quads)
#pragma unroll
    for (int nt = 0; nt < 2; nt++) {
      float mx = -3.0e38f;
#pragma unroll
      for (int mt = 0; mt < 8; mt++)
#pragma unroll
        for (int r = 0; r < 4; r++) mx = fmaxf(mx, st[mt][nt][r]);
      mx = fmaxf(mx, __shfl_xor(mx, 16));
      mx = fmaxf(mx, __shfl_xor(mx, 32));
      const float mnew = fmaxf(ms[nt], mx);
      const float alpha = __expf(ms[nt] - mnew);
      float sum = 0.f;
      const int prow = nt * 16 + c16;
      const size_t pbase = (size_t)w * 8192 + (size_t)prow * 256;
#pragma unroll
      for (int mt = 0; mt < 8; mt++) {
        float p0 = __expf(st[mt][nt][0] - mnew);
        float p1 = __expf(st[mt][nt][1] - mnew);
        float p2 = __expf(st[mt][nt][2] - mnew);
        float p3 = __expf(st[mt][nt][3] - mnew);
        sum += p0 + p1 + p2 + p3;
        const unsigned int lo = (unsigned int)f2bf(p0) | ((unsigned int)f2bf(p1) << 16);
        const unsigned int hi = (unsigned int)f2bf(p2) | ((unsigned int)f2bf(p3) << 16);
        const int chunk = mt * 2 + (quad >> 1);
        uint2* dst = (uint2*)((char*)lP + pbase + ((chunk ^ (prow & 15)) << 4) + (quad & 1) * 8);
        *dst = make_uint2(lo, hi);
      }
      sum += __shfl_xor(sum, 16);
      sum += __shfl_xor(sum, 32);
      ls[nt] = alpha * ls[nt] + sum;
      ms[nt] = mnew;
#pragma unroll
      for (int mt = 0; mt < 4; mt++) o[mt][nt] *= alpha;
    }
    // lP is same-wave write->read (in order): no barrier.

    // ---- O^T += Vt . P^T : D[d][q]
#pragma unroll
    for (int kc = 0; kc < 4; kc++) {
      bf16x8 pb[2];
#pragma unroll
      for (int nt = 0; nt < 2; nt++) {
        const int prow = nt * 16 + c16;
        const int chunk = kc * 4 + quad;
        pb[nt] = *(const bf16x8*)((const char*)lP + (size_t)w * 8192 + (size_t)prow * 256 +
                                  ((chunk ^ (prow & 15)) << 4));
      }
#pragma unroll
      for (int mt = 0; mt < 4; mt++) {
        const int d = mt * 16 + c16;
        bf16x8 a = *(const bf16x8*)((const char*)lV + d * 256 + (((kc * 4 + quad) ^ (d & 15)) * 16));
        o[mt][0] = mfma16(a, pb[0], o[mt][0]);
        o[mt][1] = mfma16(a, pb[1], o[mt][1]);
      }
    }

    if (j == jmax) break;
    __syncthreads();          // all waves done reading lK/lV(j)
    write_tile();             // LDS <- tile j+1 (vmcnt drained by compiler)
    if (j + 2 <= jmax) load_tile(j + 2);  // prefetch: lands during compute(j+1)
    __syncthreads();          // tile j+1 visible
  }

  // ---- epilogue: Ob[s][h*64+d] = O^T[d][s] / l   (bf16, 8B stores)
#pragma unroll
  for (int nt = 0; nt < 2; nt++) {
    const float inv = 1.f / ls[nt];
    const int qg = q0w + nt * 16 + c16;
#pragma unroll
    for (int mt = 0; mt < 4; mt++) {
      uint16_t tmp[4];
#pragma unroll
      for (int r = 0; r < 4; r++) tmp[r] = f2bf(o[mt][nt][r] * inv);
      *(uint2*)(Ob + (size_t)qg * 1024 + h * 64 + mt * 16 + quad * 4) = *(const uint2*)tmp;
    }
  }
}

// ---------------------------------------------------------------------------
extern "C" void kernel_launch(void* const* d_in, const int* in_sizes, int n_in,
                              void* d_out, int out_size, void* d_ws, size_t ws_size,
                              hipStream_t stream) {
  const float* x      = (const float*)d_in[0];   // fp32 [1][4096][1024]
  // d_in[1] = attention_mask (fp32): analytically causal, never read
  const float* W_attn = (const float*)d_in[2];   // fp32 [1024][3072]
  const float* b_attn = (const float*)d_in[3];   // fp32 [3072]
  const float* W_proj = (const float*)d_in[4];   // fp32 [1024][1024]
  const float* b_proj = (const float*)d_in[5];   // fp32 [1024]
  float* out = (float*)d_out;                    // fp32 [4096][1024]

  // Workspace (48 MB).
  char* ws = (char*)d_ws;
  uint16_t* Ob  = (uint16_t*)(ws);                    // [0,8MB): attn out bf16 [4096][1024]
  uint16_t* wtA = (uint16_t*)(ws + 8388608);          // [8,14MB): W_attn^T bf16 [3072][1024]
  uint16_t* wtP = (uint16_t*)(ws + 14680064);         // [14,16MB): W_proj^T bf16 [1024][1024]
  uint16_t* Qb  = (uint16_t*)(ws + 16777216);         // [16,24MB): Q bf16 (prescaled 1/8)
  uint16_t* Kb  = (uint16_t*)(ws + 25165824);         // [24,32MB): K bf16
  uint16_t* Vtb = (uint16_t*)(ws + 33554432);         // [32,40MB): V^T bf16
  uint16_t* xb  = (uint16_t*)(ws + 41943040);         // [40,48MB): x bf16 [4096][1024]

  f2b_k<<<2048, 256, 0, stream>>>(x, xb, 4096 * 1024);
  transpose_f2b<<<dim3(48, 16), 256, 0, stream>>>(W_attn, wtA, 1024, 3072);
  transpose_f2b<<<dim3(16, 16), 256, 0, stream>>>(W_proj, wtP, 1024, 1024);
  gemm_bt<0><<<dim3(24, 32), 256, 0, stream>>>(xb, wtA, b_attn, Qb, Kb, Vtb, nullptr);
  attn_kernel<<<dim3(512), 256, 0, stream>>>(Qb, Kb, Vtb, Ob);
  gemm_bt<1><<<dim3(8, 32), 256, 0, stream>>>(Ob, wtP, b_proj, nullptr, nullptr, nullptr, out);
}